// Round 5
// baseline (37.869 us; speedup 1.0000x reference)
//
#include <hip/hip_runtime.h>

#define TPB 256
#define PPB 128             // points per block (2 lanes cooperate per point)
#define NBLK 1364           // 174592 / 128  -> 5.33 blocks/CU, single dispatch round
#define GNUM 50
#define INF_ 1000000.0f

// Shared pieces of the focal-loss element math, in terms of a=|x|:
//   e = exp(-a), ln = log(1+e) = softplus(-a), s = 1/(1+e)
//   s2 = s^2 ; apl = a+ln = softplus(a) ; bb = e^2 * ln
// non-target term = s2 * (x>=0 ? apl : bb); target term = s2 * (x>=0 ? bb : apl)
__device__ __forceinline__ void sp_parts(float xx, float& s2, float& apl, float& bb) {
    float a  = fabsf(xx);
    float e  = __expf(-a);
    float t  = 1.0f + e;
    float r  = __builtin_amdgcn_rcpf(t);
    float ln = __logf(t);
    s2  = r * r;
    apl = a + ln;
    bb  = e * e * ln;
}

__global__ __launch_bounds__(TPB, 8) void fcos_main(
    const float* __restrict__ pred_class,
    const float4* __restrict__ pred_bbox,
    const float* __restrict__ pred_ctr,
    const float4* __restrict__ gt_boxes,
    const int* __restrict__ gt_labels,
    float* __restrict__ partials)
{
    __shared__ float wpart[4][5];

    const int tid = threadIdx.x;
    const int sub = tid & 1;        // 2 lanes cooperate on one point
    const int pt  = tid >> 1;       // local point 0..127
    const int k   = (blockIdx.x << 7) + pt;

    // ---- issue all 10 coalesced float4 class loads up front (independent) ----
    const float4* pc4 = (const float4*)pred_class + (size_t)blockIdx.x * (PPB * 20);
    float4 v[10];
    #pragma unroll
    for (int it = 0; it < 10; ++it) v[it] = pc4[tid + it * TPB];

    // ---- per-point decode (level branches are block-uniform: boundaries %128==0) ----
    int li, b, p;
    if (k < 131072)      { li = 0; b = k >> 14;               p = k & 16383; }
    else if (k < 163840) { li = 1; int r = k - 131072; b = r >> 12; p = r & 4095; }
    else if (k < 172032) { li = 2; int r = k - 163840; b = r >> 10; p = r & 1023; }
    else if (k < 174080) { li = 3; int r = k - 172032; b = r >> 8;  p = r & 255; }
    else                 { li = 4; int r = k - 174080; b = r >> 6;  p = r & 63; }

    const int logn = 7 - li;
    const float sF = (float)(8 << li);
    const float x = ((float)(p & ((1 << logn) - 1)) + 0.5f) * sF;
    const float y = ((float)(p >> logn) + 0.5f) * sF;
    const float lo = (li == 0) ? -1.0f : (float)(64 << (li - 1));
    const float hi = (li == 4) ? INF_ : (float)(64 << li);

    // ---- GT assignment: 2 sub-lanes scan 25 contiguous GTs each (50 exactly) ----
    const float4* gb = gt_boxes + b * GNUM;
    float best = INF_;
    int bi = GNUM;
    #pragma unroll 5
    for (int j = 0; j < 25; ++j) {
        int g = sub * 25 + j;       // contiguous chunk preserves argmin ordering
        float4 bx = gb[g];
        float l  = x - bx.x;
        float t  = y - bx.y;
        float r  = bx.z - x;
        float bt = bx.w - y;
        float mn = fminf(fminf(l, t), fminf(r, bt));
        float mx = fmaxf(fmaxf(l, t), fmaxf(r, bt));
        float area = (bx.z - bx.x) * (bx.w - bx.y);
        bool ok = (mn > 0.0f) && (mx >= lo) && (mx <= hi);
        float m = ok ? area : INF_;
        if (m < best) { best = m; bi = g; }
    }
    {   // lexicographic (area, idx) merge across the 2 sub-lanes
        float ob = __shfl_xor(best, 1);
        int   oi = __shfl_xor(bi, 1);
        if (ob < best || (ob == best && oi < bi)) { best = ob; bi = oi; }
    }

    const bool pos = best < INF_;
    float ctr = 0.0f, lbox = 0.0f, bce = 0.0f, posf = 0.0f, cls = 0.0f;
    if (sub == 0 && pos) {
        posf = 1.0f;
        int lab = gt_labels[b * GNUM + bi] - 1;     // 0..79
        float4 bx = gb[bi];
        float wl = x - bx.x, wt = y - bx.y, wr = bx.z - x, wb = bx.w - y;

        float num = fminf(wl, wr) * fminf(wt, wb);
        float den = fmaxf(wl, wr) * fmaxf(wt, wb) + 1e-12f;
        ctr = __builtin_amdgcn_sqrtf(fminf(fmaxf(num * __builtin_amdgcn_rcpf(den), 0.0f), 1.0f));

        float4 d = pred_bbox[k];
        float px1 = x - d.x, py1 = y - d.y, px2 = x + d.z, py2 = y + d.w;
        float tx1 = x - wl,  ty1 = y - wt,  tx2 = x + wr,  ty2 = y + wb;
        float ix1 = fmaxf(px1, tx1), iy1 = fmaxf(py1, ty1);
        float ix2 = fminf(px2, tx2), iy2 = fminf(py2, ty2);
        float inter = fmaxf(ix2 - ix1, 0.0f) * fmaxf(iy2 - iy1, 0.0f);
        float ap = fmaxf(px2 - px1, 0.0f) * fmaxf(py2 - py1, 0.0f);
        float at = fmaxf(tx2 - tx1, 0.0f) * fmaxf(ty2 - ty1, 0.0f);
        float iou = inter * __builtin_amdgcn_rcpf(ap + at - inter + 1e-7f);
        lbox = -__logf(fminf(fmaxf(iou, 1e-6f), 1.0f)) * ctr;

        float pc = pred_ctr[k];
        float e  = __expf(-fabsf(pc));
        float l1 = __logf(1.0f + e);
        float sp_p = fmaxf(pc, 0.0f) + l1;
        float sp_n = fmaxf(-pc, 0.0f) + l1;
        bce = ctr * sp_n + (1.0f - ctr) * sp_p;

        // focal correction for this point's target element:
        // phase 2 adds 0.75*nontarget for it; true value is 0.25*target.
        float xx = pred_class[(size_t)k * 80 + lab];
        float s2c, aplc, bbc;
        sp_parts(xx, s2c, aplc, bbc);
        float nt = (xx >= 0.0f) ? aplc : bbc;
        float tg = (xx >= 0.0f) ? bbc : aplc;
        cls = s2c * fmaf(0.25f, tg, -0.75f * nt);
    }

    // ---- phase 2: non-target focal term for ALL elements (label-free) ----
    float acc2 = 0.0f;
    #pragma unroll
    for (int it = 0; it < 10; ++it) {
        float vv[4] = {v[it].x, v[it].y, v[it].z, v[it].w};
        #pragma unroll
        for (int j = 0; j < 4; ++j) {
            float s2, apl, bb;
            sp_parts(vv[j], s2, apl, bb);
            float sel = (vv[j] >= 0.0f) ? apl : bb;
            acc2 = fmaf(s2, sel, acc2);
        }
    }
    cls = fmaf(0.75f, acc2, cls);

    // ---- deterministic block reduction of 5 sums ----
    float v5[5] = {cls, lbox, bce, posf, ctr};
    #pragma unroll
    for (int off = 32; off >= 1; off >>= 1) {
        #pragma unroll
        for (int s2 = 0; s2 < 5; ++s2) v5[s2] += __shfl_down(v5[s2], off);
    }
    const int lane = tid & 63, wid = tid >> 6;
    if (lane == 0) {
        #pragma unroll
        for (int s2 = 0; s2 < 5; ++s2) wpart[wid][s2] = v5[s2];
    }
    __syncthreads();
    if (tid == 0) {
        #pragma unroll
        for (int s2 = 0; s2 < 5; ++s2)
            partials[s2 * NBLK + blockIdx.x] =
                wpart[0][s2] + wpart[1][s2] + wpart[2][s2] + wpart[3][s2];
    }
}

__global__ __launch_bounds__(TPB) void fcos_final(
    const float* __restrict__ partials, float* __restrict__ out)
{
    const int tid = threadIdx.x;
    float acc[5] = {0, 0, 0, 0, 0};
    for (int i = tid; i < NBLK; i += TPB) {
        #pragma unroll
        for (int s2 = 0; s2 < 5; ++s2) acc[s2] += partials[s2 * NBLK + i];
    }
    #pragma unroll
    for (int off = 32; off >= 1; off >>= 1) {
        #pragma unroll
        for (int s2 = 0; s2 < 5; ++s2) acc[s2] += __shfl_down(acc[s2], off);
    }
    __shared__ float wp[4][5];
    const int lane = tid & 63, wid = tid >> 6;
    if (lane == 0) {
        #pragma unroll
        for (int s2 = 0; s2 < 5; ++s2) wp[wid][s2] = acc[s2];
    }
    __syncthreads();
    if (tid == 0) {
        float S[5];
        #pragma unroll
        for (int s2 = 0; s2 < 5; ++s2)
            S[s2] = wp[0][s2] + wp[1][s2] + wp[2][s2] + wp[3][s2];
        float pos_num = fmaxf(S[3], 1.0f);
        float denorm  = fmaxf(S[4], 1e-6f);
        out[0] = S[0] / pos_num;   // loss_cls
        out[1] = S[1] / denorm;    // loss_box
        out[2] = S[2] / pos_num;   // loss_ctr
    }
}

extern "C" void kernel_launch(void* const* d_in, const int* in_sizes, int n_in,
                              void* d_out, int out_size, void* d_ws, size_t ws_size,
                              hipStream_t stream) {
    const float*  pred_class = (const float*)d_in[0];
    const float4* pred_bbox  = (const float4*)d_in[1];
    const float*  pred_ctr   = (const float*)d_in[2];
    const float4* gt_boxes   = (const float4*)d_in[3];
    const int*    gt_labels  = (const int*)d_in[4];
    float* partials = (float*)d_ws;          // 5 * NBLK floats, fully rewritten each call
    float* out = (float*)d_out;

    fcos_main<<<NBLK, TPB, 0, stream>>>(pred_class, pred_bbox, pred_ctr,
                                        gt_boxes, gt_labels, partials);
    fcos_final<<<1, TPB, 0, stream>>>(partials, out);
}

// Round 6
// 28.024 us; speedup vs baseline: 1.3513x; 1.3513x over previous
//
#include <hip/hip_runtime.h>

#define TPB 256
#define PPB 64              // points per block (4 lanes cooperate per point)
#define NBLK 2728           // 174592 / 64
#define TPB_F 1024
#define GNUM 50
#define INF_ 1000000.0f

// Shared pieces of the focal-loss element math, in terms of a=|x|:
//   e = exp(-a), ln = log(1+e) = softplus(-a), s = 1/(1+e)
//   s2 = s^2 ; apl = a+ln = softplus(a) ; bb = e^2 * ln
// non-target term = s2 * (x>=0 ? apl : bb); target term = s2 * (x>=0 ? bb : apl)
__device__ __forceinline__ void sp_parts(float xx, float& s2, float& apl, float& bb) {
    float a  = fabsf(xx);
    float e  = __expf(-a);
    float t  = 1.0f + e;
    float r  = __builtin_amdgcn_rcpf(t);
    float ln = __logf(t);
    s2  = r * r;
    apl = a + ln;
    bb  = e * e * ln;
}

__global__ __launch_bounds__(TPB) void fcos_main(
    const float* __restrict__ pred_class,
    const float4* __restrict__ pred_bbox,
    const float* __restrict__ pred_ctr,
    const float4* __restrict__ gt_boxes,
    const int* __restrict__ gt_labels,
    float* __restrict__ partials)
{
    __shared__ float wpart[4][5];

    const int tid = threadIdx.x;
    const int sub = tid & 3;        // 4 lanes cooperate on one point
    const int pt  = tid >> 2;       // local point 0..63
    const int k0  = blockIdx.x << 6;
    const int k   = k0 + pt;

    // ---- issue the 5 coalesced float4 class loads up front (independent) ----
    const float4* pc4 = (const float4*)pred_class + (size_t)blockIdx.x * (PPB * 20);
    float4 v[5];
    #pragma unroll
    for (int it = 0; it < 5; ++it) v[it] = pc4[tid + it * TPB];

    // ---- hoist the positive-branch point loads: latency hides under assignment ----
    float4 dpred = make_float4(0.f, 0.f, 0.f, 0.f);
    float  pcv   = 0.f;
    if (sub == 0) { dpred = pred_bbox[k]; pcv = pred_ctr[k]; }

    // ---- decode block -> (level, batch, point-base); uniform per block ----
    int li, b, p0;
    if (k0 < 131072)      { li = 0; int r = k0;          b = r >> 14; p0 = r & 16383; }
    else if (k0 < 163840) { li = 1; int r = k0 - 131072; b = r >> 12; p0 = r & 4095; }
    else if (k0 < 172032) { li = 2; int r = k0 - 163840; b = r >> 10; p0 = r & 1023; }
    else if (k0 < 174080) { li = 3; int r = k0 - 172032; b = r >> 8;  p0 = r & 255; }
    else                  { li = 4; int r = k0 - 174080; b = r >> 6;  p0 = r & 63; }

    const int p = p0 + pt;
    const int logn = 7 - li;
    const float sF = (float)(8 << li);
    const float x = ((float)(p & ((1 << logn) - 1)) + 0.5f) * sF;
    const float y = ((float)(p >> logn) + 0.5f) * sF;
    const float lo = (li == 0) ? -1.0f : (float)(64 << (li - 1));
    const float hi = (li == 4) ? INF_ : (float)(64 << li);

    // ---- GT assignment: 4 sub-lanes scan 13 contiguous GTs each ----
    const float4* gb = gt_boxes + b * GNUM;
    float best = INF_;
    int bi = GNUM;
    #pragma unroll
    for (int j = 0; j < 13; ++j) {
        int g = sub * 13 + j;
        int gg = min(g, GNUM - 1);
        float4 bx = gb[gg];
        float l  = x - bx.x;
        float t  = y - bx.y;
        float r  = bx.z - x;
        float bt = bx.w - y;
        float mn = fminf(fminf(l, t), fminf(r, bt));
        float mx = fmaxf(fmaxf(l, t), fmaxf(r, bt));
        float area = (bx.z - bx.x) * (bx.w - bx.y);
        bool ok = (mn > 0.0f) && (mx >= lo) && (mx <= hi) && (g < GNUM);
        float m = ok ? area : INF_;
        if (m < best) { best = m; bi = g; }
    }
    #pragma unroll
    for (int off = 1; off <= 2; off <<= 1) {
        float ob = __shfl_xor(best, off);
        int   oi = __shfl_xor(bi, off);
        if (ob < best || (ob == best && oi < bi)) { best = ob; bi = oi; }
    }

    const bool pos = best < INF_;
    float ctr = 0.0f, lbox = 0.0f, bce = 0.0f, posf = 0.0f, cls = 0.0f;
    if (sub == 0 && pos) {
        posf = 1.0f;
        int lab = gt_labels[b * GNUM + bi] - 1;     // 0..79
        float4 bx = gb[bi];
        float wl = x - bx.x, wt = y - bx.y, wr = bx.z - x, wb = bx.w - y;

        float num = fminf(wl, wr) * fminf(wt, wb);
        float den = fmaxf(wl, wr) * fmaxf(wt, wb) + 1e-12f;
        ctr = __builtin_amdgcn_sqrtf(fminf(fmaxf(num * __builtin_amdgcn_rcpf(den), 0.0f), 1.0f));

        float px1 = x - dpred.x, py1 = y - dpred.y, px2 = x + dpred.z, py2 = y + dpred.w;
        float tx1 = x - wl,  ty1 = y - wt,  tx2 = x + wr,  ty2 = y + wb;
        float ix1 = fmaxf(px1, tx1), iy1 = fmaxf(py1, ty1);
        float ix2 = fminf(px2, tx2), iy2 = fminf(py2, ty2);
        float inter = fmaxf(ix2 - ix1, 0.0f) * fmaxf(iy2 - iy1, 0.0f);
        float ap = fmaxf(px2 - px1, 0.0f) * fmaxf(py2 - py1, 0.0f);
        float at = fmaxf(tx2 - tx1, 0.0f) * fmaxf(ty2 - ty1, 0.0f);
        float iou = inter * __builtin_amdgcn_rcpf(ap + at - inter + 1e-7f);
        lbox = -__logf(fminf(fmaxf(iou, 1e-6f), 1.0f)) * ctr;

        float e  = __expf(-fabsf(pcv));
        float l1 = __logf(1.0f + e);
        float sp_p = fmaxf(pcv, 0.0f) + l1;
        float sp_n = fmaxf(-pcv, 0.0f) + l1;
        bce = ctr * sp_n + (1.0f - ctr) * sp_p;

        // focal correction for this point's target element:
        // phase 2 adds 0.75*nontarget for it; true value is 0.25*target.
        float xx = pred_class[(size_t)k * 80 + lab];
        float s2c, aplc, bbc;
        sp_parts(xx, s2c, aplc, bbc);
        float nt = (xx >= 0.0f) ? aplc : bbc;
        float tg = (xx >= 0.0f) ? bbc : aplc;
        cls = s2c * fmaf(0.25f, tg, -0.75f * nt);
    }

    // ---- phase 2: non-target focal term for ALL elements (label-free) ----
    float acc2 = 0.0f;
    #pragma unroll
    for (int it = 0; it < 5; ++it) {
        float vv[4] = {v[it].x, v[it].y, v[it].z, v[it].w};
        #pragma unroll
        for (int j = 0; j < 4; ++j) {
            float s2, apl, bb;
            sp_parts(vv[j], s2, apl, bb);
            float sel = (vv[j] >= 0.0f) ? apl : bb;
            acc2 = fmaf(s2, sel, acc2);
        }
    }
    cls = fmaf(0.75f, acc2, cls);

    // ---- deterministic block reduction of 5 sums ----
    float v5[5] = {cls, lbox, bce, posf, ctr};
    #pragma unroll
    for (int off = 32; off >= 1; off >>= 1) {
        #pragma unroll
        for (int s2 = 0; s2 < 5; ++s2) v5[s2] += __shfl_down(v5[s2], off);
    }
    const int lane = tid & 63, wid = tid >> 6;
    if (lane == 0) {
        #pragma unroll
        for (int s2 = 0; s2 < 5; ++s2) wpart[wid][s2] = v5[s2];
    }
    __syncthreads();
    if (tid == 0) {
        #pragma unroll
        for (int s2 = 0; s2 < 5; ++s2)
            partials[s2 * NBLK + blockIdx.x] =
                wpart[0][s2] + wpart[1][s2] + wpart[2][s2] + wpart[3][s2];
    }
}

__global__ __launch_bounds__(TPB_F) void fcos_final(
    const float* __restrict__ partials, float* __restrict__ out)
{
    const int tid = threadIdx.x;
    float acc[5] = {0, 0, 0, 0, 0};
    for (int i = tid; i < NBLK; i += TPB_F) {
        #pragma unroll
        for (int s2 = 0; s2 < 5; ++s2) acc[s2] += partials[s2 * NBLK + i];
    }
    #pragma unroll
    for (int off = 32; off >= 1; off >>= 1) {
        #pragma unroll
        for (int s2 = 0; s2 < 5; ++s2) acc[s2] += __shfl_down(acc[s2], off);
    }
    __shared__ float wp[16][5];
    const int lane = tid & 63, wid = tid >> 6;
    if (lane == 0) {
        #pragma unroll
        for (int s2 = 0; s2 < 5; ++s2) wp[wid][s2] = acc[s2];
    }
    __syncthreads();
    if (tid == 0) {
        float S[5];
        #pragma unroll
        for (int s2 = 0; s2 < 5; ++s2) {
            float s = 0.0f;
            #pragma unroll
            for (int w = 0; w < 16; ++w) s += wp[w][s2];
            S[s2] = s;
        }
        float pos_num = fmaxf(S[3], 1.0f);
        float denorm  = fmaxf(S[4], 1e-6f);
        out[0] = S[0] / pos_num;   // loss_cls
        out[1] = S[1] / denorm;    // loss_box
        out[2] = S[2] / pos_num;   // loss_ctr
    }
}

extern "C" void kernel_launch(void* const* d_in, const int* in_sizes, int n_in,
                              void* d_out, int out_size, void* d_ws, size_t ws_size,
                              hipStream_t stream) {
    const float*  pred_class = (const float*)d_in[0];
    const float4* pred_bbox  = (const float4*)d_in[1];
    const float*  pred_ctr   = (const float*)d_in[2];
    const float4* gt_boxes   = (const float4*)d_in[3];
    const int*    gt_labels  = (const int*)d_in[4];
    float* partials = (float*)d_ws;          // 5 * NBLK floats, fully rewritten each call
    float* out = (float*)d_out;

    fcos_main<<<NBLK, TPB, 0, stream>>>(pred_class, pred_bbox, pred_ctr,
                                        gt_boxes, gt_labels, partials);
    fcos_final<<<1, TPB_F, 0, stream>>>(partials, out);
}

// Round 7
// 27.100 us; speedup vs baseline: 1.3974x; 1.0341x over previous
//
#include <hip/hip_runtime.h>

#define TPB 256
#define ABLK 682            // assignment blocks: 1 thread per point, 256 pts/block
#define SBLK 2728           // streaming blocks: 1280 float4s each (= 64 pts x 80 cls)
#define GRID 3410           // interleaved 1:4  (bid % 5 == 0 -> assignment)
#define TPB_F 1024
#define GNUM 50
#define INF_ 1000000.0f

// Focal-loss element math, in terms of a=|x|:
//   e = exp(-a), ln = log(1+e), s = 1/(1+e)
//   s2 = s^2 ; apl = a+ln = softplus(a) ; bb = e^2 * ln
// non-target term = s2 * (x>=0 ? apl : bb); target term = s2 * (x>=0 ? bb : apl)
__device__ __forceinline__ void sp_parts(float xx, float& s2, float& apl, float& bb) {
    float a  = fabsf(xx);
    float e  = __expf(-a);
    float t  = 1.0f + e;
    float r  = __builtin_amdgcn_rcpf(t);
    float ln = __logf(t);
    s2  = r * r;
    apl = a + ln;
    bb  = e * e * ln;
}

// partials layout in d_ws:
//   [s*ABLK + q]        s=0..4 : assign {cls_corr, lbox, bce, posf, ctr}
//   [5*ABLK + sidx]              : stream 0.75*focal_nontarget block sums
__global__ __launch_bounds__(TPB) void fcos_fat(
    const float* __restrict__ pred_class,
    const float4* __restrict__ pred_bbox,
    const float* __restrict__ pred_ctr,
    const float4* __restrict__ gt_boxes,
    const int* __restrict__ gt_labels,
    float* __restrict__ partials)
{
    const int tid = threadIdx.x;
    const int bid = blockIdx.x;
    const int q = bid / 5;
    const int r = bid - q * 5;
    const int lane = tid & 63, wid = tid >> 6;

    if (r != 0) {
        // ================= streaming block: label-free focal sum =================
        __shared__ float wsum[4];
        const int s = q * 4 + (r - 1);      // 0..2727
        const float4* pc4 = (const float4*)pred_class + (size_t)s * 1280;
        float4 v[5];
        #pragma unroll
        for (int it = 0; it < 5; ++it) v[it] = pc4[tid + it * TPB];

        float a0 = 0.f, a1 = 0.f, a2 = 0.f, a3 = 0.f;   // 4 independent chains
        #pragma unroll
        for (int it = 0; it < 5; ++it) {
            float s2, apl, bb;
            sp_parts(v[it].x, s2, apl, bb); a0 = fmaf(s2, (v[it].x >= 0.f) ? apl : bb, a0);
            sp_parts(v[it].y, s2, apl, bb); a1 = fmaf(s2, (v[it].y >= 0.f) ? apl : bb, a1);
            sp_parts(v[it].z, s2, apl, bb); a2 = fmaf(s2, (v[it].z >= 0.f) ? apl : bb, a2);
            sp_parts(v[it].w, s2, apl, bb); a3 = fmaf(s2, (v[it].w >= 0.f) ? apl : bb, a3);
        }
        float acc = 0.75f * ((a0 + a1) + (a2 + a3));
        #pragma unroll
        for (int off = 32; off >= 1; off >>= 1) acc += __shfl_down(acc, off);
        if (lane == 0) wsum[wid] = acc;
        __syncthreads();
        if (tid == 0)
            partials[5 * ABLK + s] = (wsum[0] + wsum[1]) + (wsum[2] + wsum[3]);
    } else {
        // ================= assignment block: 1 thread per point =================
        __shared__ float wpart[4][5];
        const int k = (q << 8) + tid;       // point index 0..174591

        // hoisted coalesced point loads (latency hides under the 50-box scan)
        float4 dpred = pred_bbox[k];
        float  pcv   = pred_ctr[k];

        // decode (level branches are block-uniform: boundaries % 256 == 0)
        int li, b, p;
        if (k < 131072)      { li = 0; b = k >> 14;               p = k & 16383; }
        else if (k < 163840) { li = 1; int t = k - 131072; b = t >> 12; p = t & 4095; }
        else if (k < 172032) { li = 2; int t = k - 163840; b = t >> 10; p = t & 1023; }
        else if (k < 174080) { li = 3; int t = k - 172032; b = t >> 8;  p = t & 255; }
        else                 { li = 4; int t = k - 174080; b = t >> 6;  p = t & 63; }

        const int logn = 7 - li;
        const float sF = (float)(8 << li);
        const float x = ((float)(p & ((1 << logn) - 1)) + 0.5f) * sF;
        const float y = ((float)(p >> logn) + 0.5f) * sF;
        const float lo = (li == 0) ? -1.0f : (float)(64 << (li - 1));
        const float hi = (li == 4) ? INF_ : (float)(64 << li);

        // full 50-box scan, strict < -> exact jnp.argmin first-occurrence
        const float4* gb = gt_boxes + b * GNUM;
        float best = INF_;
        int bi = 0;
        #pragma unroll 5
        for (int g = 0; g < GNUM; ++g) {
            float4 bx = gb[g];
            float l  = x - bx.x;
            float t  = y - bx.y;
            float rr = bx.z - x;
            float bt = bx.w - y;
            float mn = fminf(fminf(l, t), fminf(rr, bt));
            float mx = fmaxf(fmaxf(l, t), fmaxf(rr, bt));
            float area = (bx.z - bx.x) * (bx.w - bx.y);
            bool ok = (mn > 0.0f) && (mx >= lo) && (mx <= hi);
            float m = ok ? area : INF_;
            if (m < best) { best = m; bi = g; }
        }

        const bool pos = best < INF_;
        float ctr = 0.0f, lbox = 0.0f, bce = 0.0f, posf = 0.0f, cls = 0.0f;
        if (pos) {
            posf = 1.0f;
            int lab = gt_labels[b * GNUM + bi] - 1;                 // 0..79
            float xx = pred_class[(size_t)k * 80 + lab];            // issue gather EARLY
            float4 bx = gb[bi];
            float wl = x - bx.x, wt = y - bx.y, wr = bx.z - x, wb = bx.w - y;

            float num = fminf(wl, wr) * fminf(wt, wb);
            float den = fmaxf(wl, wr) * fmaxf(wt, wb) + 1e-12f;
            ctr = __builtin_amdgcn_sqrtf(
                      fminf(fmaxf(num * __builtin_amdgcn_rcpf(den), 0.0f), 1.0f));

            float px1 = x - dpred.x, py1 = y - dpred.y, px2 = x + dpred.z, py2 = y + dpred.w;
            float tx1 = x - wl,  ty1 = y - wt,  tx2 = x + wr,  ty2 = y + wb;
            float ix1 = fmaxf(px1, tx1), iy1 = fmaxf(py1, ty1);
            float ix2 = fminf(px2, tx2), iy2 = fminf(py2, ty2);
            float inter = fmaxf(ix2 - ix1, 0.0f) * fmaxf(iy2 - iy1, 0.0f);
            float ap = fmaxf(px2 - px1, 0.0f) * fmaxf(py2 - py1, 0.0f);
            float at = fmaxf(tx2 - tx1, 0.0f) * fmaxf(ty2 - ty1, 0.0f);
            float iou = inter * __builtin_amdgcn_rcpf(ap + at - inter + 1e-7f);
            lbox = -__logf(fminf(fmaxf(iou, 1e-6f), 1.0f)) * ctr;

            float e  = __expf(-fabsf(pcv));
            float l1 = __logf(1.0f + e);
            float sp_p = fmaxf(pcv, 0.0f) + l1;
            float sp_n = fmaxf(-pcv, 0.0f) + l1;
            bce = ctr * sp_n + (1.0f - ctr) * sp_p;

            // focal correction for the target element:
            // streaming adds 0.75*nontarget for it; true value is 0.25*target.
            float s2c, aplc, bbc;
            sp_parts(xx, s2c, aplc, bbc);
            float nt = (xx >= 0.0f) ? aplc : bbc;
            float tg = (xx >= 0.0f) ? bbc : aplc;
            cls = s2c * fmaf(0.25f, tg, -0.75f * nt);
        }

        float v5[5] = {cls, lbox, bce, posf, ctr};
        #pragma unroll
        for (int off = 32; off >= 1; off >>= 1) {
            #pragma unroll
            for (int s2 = 0; s2 < 5; ++s2) v5[s2] += __shfl_down(v5[s2], off);
        }
        if (lane == 0) {
            #pragma unroll
            for (int s2 = 0; s2 < 5; ++s2) wpart[wid][s2] = v5[s2];
        }
        __syncthreads();
        if (tid == 0) {
            #pragma unroll
            for (int s2 = 0; s2 < 5; ++s2)
                partials[s2 * ABLK + q] =
                    (wpart[0][s2] + wpart[1][s2]) + (wpart[2][s2] + wpart[3][s2]);
        }
    }
}

__global__ __launch_bounds__(TPB_F) void fcos_final(
    const float* __restrict__ partials, float* __restrict__ out)
{
    const int tid = threadIdx.x;
    float acc[5] = {0, 0, 0, 0, 0};
    float accs = 0.0f;
    for (int i = tid; i < ABLK; i += TPB_F) {
        #pragma unroll
        for (int s2 = 0; s2 < 5; ++s2) acc[s2] += partials[s2 * ABLK + i];
    }
    for (int i = tid; i < SBLK; i += TPB_F) accs += partials[5 * ABLK + i];
    #pragma unroll
    for (int off = 32; off >= 1; off >>= 1) {
        #pragma unroll
        for (int s2 = 0; s2 < 5; ++s2) acc[s2] += __shfl_down(acc[s2], off);
        accs += __shfl_down(accs, off);
    }
    __shared__ float wp[16][6];
    const int lane = tid & 63, wid = tid >> 6;
    if (lane == 0) {
        #pragma unroll
        for (int s2 = 0; s2 < 5; ++s2) wp[wid][s2] = acc[s2];
        wp[wid][5] = accs;
    }
    __syncthreads();
    if (tid == 0) {
        float S[6];
        #pragma unroll
        for (int s2 = 0; s2 < 6; ++s2) {
            float s = 0.0f;
            #pragma unroll
            for (int w = 0; w < 16; ++w) s += wp[w][s2];
            S[s2] = s;
        }
        float pos_num = fmaxf(S[3], 1.0f);
        float denorm  = fmaxf(S[4], 1e-6f);
        out[0] = (S[0] + S[5]) / pos_num;   // loss_cls = (corr + stream)/pos_num
        out[1] = S[1] / denorm;             // loss_box
        out[2] = S[2] / pos_num;            // loss_ctr
    }
}

extern "C" void kernel_launch(void* const* d_in, const int* in_sizes, int n_in,
                              void* d_out, int out_size, void* d_ws, size_t ws_size,
                              hipStream_t stream) {
    const float*  pred_class = (const float*)d_in[0];
    const float4* pred_bbox  = (const float4*)d_in[1];
    const float*  pred_ctr   = (const float*)d_in[2];
    const float4* gt_boxes   = (const float4*)d_in[3];
    const int*    gt_labels  = (const int*)d_in[4];
    float* partials = (float*)d_ws;          // (5*ABLK + SBLK) floats, fully rewritten
    float* out = (float*)d_out;

    fcos_fat<<<GRID, TPB, 0, stream>>>(pred_class, pred_bbox, pred_ctr,
                                       gt_boxes, gt_labels, partials);
    fcos_final<<<1, TPB_F, 0, stream>>>(partials, out);
}

// Round 10
// 25.861 us; speedup vs baseline: 1.4643x; 1.0479x over previous
//
#include <hip/hip_runtime.h>

#define TPB 256
#define ABLK 682            // assignment blocks: 1 thread per point, 256 pts/block
#define SBLK 1705           // streaming blocks: 2048 float4s each (8 per thread)
#define GRID 2387           // 341 groups of 7: 2 assign + 5 stream
#define TPB_F 1024
#define GNUM 50
#define INF_ 1000000.0f
#define L2E  1.44269504088896f
#define C_STREAM 0.519860385f   // 0.75 * ln2

// Focal-loss element math for the assign-side correction, in terms of a=|x|:
//   e = exp(-a), ln = log(1+e), s = 1/(1+e)
//   s2 = s^2 ; apl = a+ln = softplus(a) ; bb = e^2 * ln
// non-target term = s2 * (x>=0 ? apl : bb); target term = s2 * (x>=0 ? bb : apl)
__device__ __forceinline__ void sp_parts(float xx, float& s2, float& apl, float& bb) {
    float a  = fabsf(xx);
    float e  = __expf(-a);
    float t  = 1.0f + e;
    float r  = __builtin_amdgcn_rcpf(t);
    float ln = __logf(t);
    s2  = r * r;
    apl = a + ln;
    bb  = e * e * ln;
}

// Streaming form: 0.75 * p^2 * softplus(x) = C_STREAM * p^2 * log2(1+e^x)
// 8 instructions: mul, exp2, add, rcp, mul, log2, mul, fma
// NOTE gfx950 builtins: __builtin_amdgcn_exp2f = v_exp_f32 = 2^x,
//                       __builtin_amdgcn_logf  = v_log_f32 = log2(x).
__device__ __forceinline__ float stream_elem(float x, float acc) {
    float t = __builtin_amdgcn_exp2f(x * L2E);     // e^x
    float u = 1.0f + t;
    float p = t * __builtin_amdgcn_rcpf(u);        // sigmoid(x)
    float lg = __builtin_amdgcn_logf(u);           // log2(1+e^x)
    return fmaf(p * p, lg, acc);                   // scale by C_STREAM once at end
}

// partials layout in d_ws (floats):
//   [s2*ABLK + a]            s2=0..4 : assign {cls_corr, lbox, bce, posf, ctr}
//   [5*ABLK + s*4 + wid]             : stream per-wave sums (4 waves/block)
__global__ __launch_bounds__(TPB) void fcos_fat(
    const float* __restrict__ pred_class,
    const float4* __restrict__ pred_bbox,
    const float* __restrict__ pred_ctr,
    const float4* __restrict__ gt_boxes,
    const int* __restrict__ gt_labels,
    float* __restrict__ partials)
{
    const int tid = threadIdx.x;
    const int bid = blockIdx.x;
    const int grp = bid / 7;
    const int r = bid - grp * 7;
    const int lane = tid & 63, wid = tid >> 6;

    if (r >= 2) {
        // ================= streaming block: label-free focal sum =================
        const int s = grp * 5 + (r - 2);      // 0..1704
        const float4* pc4 = (const float4*)pred_class + (size_t)s * 2048;
        float4 v[8];
        #pragma unroll
        for (int it = 0; it < 8; ++it) v[it] = pc4[tid + it * TPB];

        float a0 = 0.f, a1 = 0.f, a2 = 0.f, a3 = 0.f;   // 4 independent chains
        #pragma unroll
        for (int it = 0; it < 8; ++it) {
            a0 = stream_elem(v[it].x, a0);
            a1 = stream_elem(v[it].y, a1);
            a2 = stream_elem(v[it].z, a2);
            a3 = stream_elem(v[it].w, a3);
        }
        float acc = C_STREAM * ((a0 + a1) + (a2 + a3));
        #pragma unroll
        for (int off = 32; off >= 1; off >>= 1) acc += __shfl_down(acc, off);
        if (lane == 0) partials[5 * ABLK + s * 4 + wid] = acc;   // wave-direct store
    } else {
        // ================= assignment block: 1 thread per point =================
        __shared__ float wpart[4][5];
        const int a = grp * 2 + r;            // 0..681
        const int k = (a << 8) + tid;         // point index 0..174591

        // hoisted coalesced point loads (latency hides under the 50-box scan)
        float4 dpred = pred_bbox[k];
        float  pcv   = pred_ctr[k];

        // decode (level branches are block-uniform: boundaries % 256 == 0)
        int li, b, p;
        if (k < 131072)      { li = 0; b = k >> 14;               p = k & 16383; }
        else if (k < 163840) { li = 1; int t = k - 131072; b = t >> 12; p = t & 4095; }
        else if (k < 172032) { li = 2; int t = k - 163840; b = t >> 10; p = t & 1023; }
        else if (k < 174080) { li = 3; int t = k - 172032; b = t >> 8;  p = t & 255; }
        else                 { li = 4; int t = k - 174080; b = t >> 6;  p = t & 63; }

        const int logn = 7 - li;
        const float sF = (float)(8 << li);
        const float x = ((float)(p & ((1 << logn) - 1)) + 0.5f) * sF;
        const float y = ((float)(p >> logn) + 0.5f) * sF;
        const float lo = (li == 0) ? -1.0f : (float)(64 << (li - 1));
        const float hi = (li == 4) ? INF_ : (float)(64 << li);

        // full 50-box scan, strict < -> exact jnp.argmin first-occurrence
        const float4* gb = gt_boxes + b * GNUM;
        float best = INF_;
        int bi = 0;
        #pragma unroll 5
        for (int g = 0; g < GNUM; ++g) {
            float4 bx = gb[g];
            float l  = x - bx.x;
            float t  = y - bx.y;
            float rr = bx.z - x;
            float bt = bx.w - y;
            float mn = fminf(fminf(l, t), fminf(rr, bt));
            float mx = fmaxf(fmaxf(l, t), fmaxf(rr, bt));
            float area = (bx.z - bx.x) * (bx.w - bx.y);
            bool ok = (mn > 0.0f) && (mx >= lo) && (mx <= hi);
            float m = ok ? area : INF_;
            if (m < best) { best = m; bi = g; }
        }

        const bool pos = best < INF_;
        float ctr = 0.0f, lbox = 0.0f, bce = 0.0f, posf = 0.0f, cls = 0.0f;
        if (pos) {
            posf = 1.0f;
            int lab = gt_labels[b * GNUM + bi] - 1;                 // 0..79
            float xx = pred_class[(size_t)k * 80 + lab];            // issue gather EARLY
            float4 bx = gb[bi];
            float wl = x - bx.x, wt = y - bx.y, wr = bx.z - x, wb = bx.w - y;

            float num = fminf(wl, wr) * fminf(wt, wb);
            float den = fmaxf(wl, wr) * fmaxf(wt, wb) + 1e-12f;
            ctr = __builtin_amdgcn_sqrtf(
                      fminf(fmaxf(num * __builtin_amdgcn_rcpf(den), 0.0f), 1.0f));

            float px1 = x - dpred.x, py1 = y - dpred.y, px2 = x + dpred.z, py2 = y + dpred.w;
            float tx1 = x - wl,  ty1 = y - wt,  tx2 = x + wr,  ty2 = y + wb;
            float ix1 = fmaxf(px1, tx1), iy1 = fmaxf(py1, ty1);
            float ix2 = fminf(px2, tx2), iy2 = fminf(py2, ty2);
            float inter = fmaxf(ix2 - ix1, 0.0f) * fmaxf(iy2 - iy1, 0.0f);
            float ap = fmaxf(px2 - px1, 0.0f) * fmaxf(py2 - py1, 0.0f);
            float at = fmaxf(tx2 - tx1, 0.0f) * fmaxf(ty2 - ty1, 0.0f);
            float iou = inter * __builtin_amdgcn_rcpf(ap + at - inter + 1e-7f);
            lbox = -__logf(fminf(fmaxf(iou, 1e-6f), 1.0f)) * ctr;

            float e  = __expf(-fabsf(pcv));
            float l1 = __logf(1.0f + e);
            float sp_p = fmaxf(pcv, 0.0f) + l1;
            float sp_n = fmaxf(-pcv, 0.0f) + l1;
            bce = ctr * sp_n + (1.0f - ctr) * sp_p;

            // focal correction for the target element:
            // streaming adds 0.75*nontarget for it; true value is 0.25*target.
            float s2c, aplc, bbc;
            sp_parts(xx, s2c, aplc, bbc);
            float nt = (xx >= 0.0f) ? aplc : bbc;
            float tg = (xx >= 0.0f) ? bbc : aplc;
            cls = s2c * fmaf(0.25f, tg, -0.75f * nt);
        }

        float v5[5] = {cls, lbox, bce, posf, ctr};
        #pragma unroll
        for (int off = 32; off >= 1; off >>= 1) {
            #pragma unroll
            for (int s2 = 0; s2 < 5; ++s2) v5[s2] += __shfl_down(v5[s2], off);
        }
        if (lane == 0) {
            #pragma unroll
            for (int s2 = 0; s2 < 5; ++s2) wpart[wid][s2] = v5[s2];
        }
        __syncthreads();
        if (tid == 0) {
            #pragma unroll
            for (int s2 = 0; s2 < 5; ++s2)
                partials[s2 * ABLK + a] =
                    (wpart[0][s2] + wpart[1][s2]) + (wpart[2][s2] + wpart[3][s2]);
        }
    }
}

__global__ __launch_bounds__(TPB_F) void fcos_final(
    const float* __restrict__ partials, float* __restrict__ out)
{
    const int tid = threadIdx.x;
    float acc[5] = {0, 0, 0, 0, 0};
    float accs = 0.0f;
    for (int i = tid; i < ABLK; i += TPB_F) {
        #pragma unroll
        for (int s2 = 0; s2 < 5; ++s2) acc[s2] += partials[s2 * ABLK + i];
    }
    for (int i = tid; i < SBLK * 4; i += TPB_F) accs += partials[5 * ABLK + i];
    #pragma unroll
    for (int off = 32; off >= 1; off >>= 1) {
        #pragma unroll
        for (int s2 = 0; s2 < 5; ++s2) acc[s2] += __shfl_down(acc[s2], off);
        accs += __shfl_down(accs, off);
    }
    __shared__ float wp[16][6];
    const int lane = tid & 63, wid = tid >> 6;
    if (lane == 0) {
        #pragma unroll
        for (int s2 = 0; s2 < 5; ++s2) wp[wid][s2] = acc[s2];
        wp[wid][5] = accs;
    }
    __syncthreads();
    if (tid == 0) {
        float S[6];
        #pragma unroll
        for (int s2 = 0; s2 < 6; ++s2) {
            float s = 0.0f;
            #pragma unroll
            for (int w = 0; w < 16; ++w) s += wp[w][s2];
            S[s2] = s;
        }
        float pos_num = fmaxf(S[3], 1.0f);
        float denorm  = fmaxf(S[4], 1e-6f);
        out[0] = (S[0] + S[5]) / pos_num;   // loss_cls = (corr + stream)/pos_num
        out[1] = S[1] / denorm;             // loss_box
        out[2] = S[2] / pos_num;            // loss_ctr
    }
}

extern "C" void kernel_launch(void* const* d_in, const int* in_sizes, int n_in,
                              void* d_out, int out_size, void* d_ws, size_t ws_size,
                              hipStream_t stream) {
    const float*  pred_class = (const float*)d_in[0];
    const float4* pred_bbox  = (const float4*)d_in[1];
    const float*  pred_ctr   = (const float*)d_in[2];
    const float4* gt_boxes   = (const float4*)d_in[3];
    const int*    gt_labels  = (const int*)d_in[4];
    float* partials = (float*)d_ws;          // (5*ABLK + 4*SBLK) floats, fully rewritten
    float* out = (float*)d_out;

    fcos_fat<<<GRID, TPB, 0, stream>>>(pred_class, pred_bbox, pred_ctr,
                                       gt_boxes, gt_labels, partials);
    fcos_final<<<1, TPB_F, 0, stream>>>(partials, out);
}

// Round 11
// 22.327 us; speedup vs baseline: 1.6961x; 1.1583x over previous
//
#include <hip/hip_runtime.h>

typedef float f32x4 __attribute__((ext_vector_type(4)));

#define TPB 256
#define ABLK 682            // assignment blocks: 1 thread per point, 256 pts/block
#define SBLK 1364           // streaming blocks: 2560 float4s each (10 per thread)
#define GRID 2046           // 682 groups of 3: stream, assign, stream
#define TPB_F 1024
#define GNUM 50
#define INF_ 1000000.0f
#define L2E  1.44269504088896f
#define C_STREAM 0.519860385f   // 0.75 * ln2

// Focal-loss element math for the assign-side correction, in terms of a=|x|:
//   e = exp(-a), ln = log(1+e), s = 1/(1+e)
//   s2 = s^2 ; apl = a+ln = softplus(a) ; bb = e^2 * ln
// non-target term = s2 * (x>=0 ? apl : bb); target term = s2 * (x>=0 ? bb : apl)
__device__ __forceinline__ void sp_parts(float xx, float& s2, float& apl, float& bb) {
    float a  = fabsf(xx);
    float e  = __expf(-a);
    float t  = 1.0f + e;
    float r  = __builtin_amdgcn_rcpf(t);
    float ln = __logf(t);
    s2  = r * r;
    apl = a + ln;
    bb  = e * e * ln;
}

// Streaming form: p^2 * log2(1+e^x)  (x0.75*ln2 folded into the finalize)
// gfx950: __builtin_amdgcn_exp2f = v_exp_f32 = 2^x; __builtin_amdgcn_logf = v_log_f32 = log2(x)
__device__ __forceinline__ float stream_elem(float x, float acc) {
    float t = __builtin_amdgcn_exp2f(x * L2E);     // e^x
    float u = 1.0f + t;
    float p = t * __builtin_amdgcn_rcpf(u);        // sigmoid(x)
    float lg = __builtin_amdgcn_logf(u);           // log2(1+e^x)
    return fmaf(p * p, lg, acc);
}

// partials layout in d_ws (floats):
//   [s2*ABLK + a]            s2=0..4 : assign {cls_corr, lbox, bce, posf, ctr}
//   [5*ABLK + s*4 + wid]             : stream per-wave raw sums (4 waves/block)
__global__ __launch_bounds__(TPB) void fcos_fat(
    const float* __restrict__ pred_class,
    const float4* __restrict__ pred_bbox,
    const float* __restrict__ pred_ctr,
    const float4* __restrict__ gt_boxes,
    const int* __restrict__ gt_labels,
    float* __restrict__ partials)
{
    const int tid = threadIdx.x;
    const int bid = blockIdx.x;
    const int grp = bid / 3;
    const int r = bid - grp * 3;
    const int lane = tid & 63, wid = tid >> 6;

    if (r != 1) {
        // ================= streaming block: label-free focal sum =================
        const int s = grp * 2 + (r >> 1);     // 0..1363
        const f32x4* pc4 = (const f32x4*)pred_class + (size_t)s * 2560;
        f32x4 v[10];
        #pragma unroll
        for (int it = 0; it < 10; ++it)
            v[it] = __builtin_nontemporal_load(pc4 + tid + it * TPB);  // 10 loads in flight

        float a0 = 0.f, a1 = 0.f, a2 = 0.f, a3 = 0.f;   // 4 independent chains
        #pragma unroll
        for (int it = 0; it < 10; ++it) {
            a0 = stream_elem(v[it].x, a0);
            a1 = stream_elem(v[it].y, a1);
            a2 = stream_elem(v[it].z, a2);
            a3 = stream_elem(v[it].w, a3);
        }
        float acc = (a0 + a1) + (a2 + a3);
        #pragma unroll
        for (int off = 32; off >= 1; off >>= 1) acc += __shfl_down(acc, off);
        if (lane == 0) partials[5 * ABLK + s * 4 + wid] = acc;   // wave-direct store
    } else {
        // ================= assignment block: 1 thread per point =================
        __shared__ float wpart[4][5];
        const int a = grp;                    // 0..681
        const int k = (a << 8) + tid;         // point index 0..174591

        // hoisted coalesced point loads (latency hides under the 50-box scan)
        float4 dpred = pred_bbox[k];
        float  pcv   = pred_ctr[k];

        // decode (level branches are block-uniform: boundaries % 256 == 0)
        int li, b, p;
        if (k < 131072)      { li = 0; b = k >> 14;               p = k & 16383; }
        else if (k < 163840) { li = 1; int t = k - 131072; b = t >> 12; p = t & 4095; }
        else if (k < 172032) { li = 2; int t = k - 163840; b = t >> 10; p = t & 1023; }
        else if (k < 174080) { li = 3; int t = k - 172032; b = t >> 8;  p = t & 255; }
        else                 { li = 4; int t = k - 174080; b = t >> 6;  p = t & 63; }

        const int logn = 7 - li;
        const float sF = (float)(8 << li);
        const float x = ((float)(p & ((1 << logn) - 1)) + 0.5f) * sF;
        const float y = ((float)(p >> logn) + 0.5f) * sF;
        const float lo = (li == 0) ? -1.0f : (float)(64 << (li - 1));
        const float hi = (li == 4) ? INF_ : (float)(64 << li);

        // full 50-box scan, strict < -> exact jnp.argmin first-occurrence
        const float4* gb = gt_boxes + b * GNUM;
        float best = INF_;
        int bi = 0;
        #pragma unroll 5
        for (int g = 0; g < GNUM; ++g) {
            float4 bx = gb[g];
            float l  = x - bx.x;
            float t  = y - bx.y;
            float rr = bx.z - x;
            float bt = bx.w - y;
            float mn = fminf(fminf(l, t), fminf(rr, bt));
            float mx = fmaxf(fmaxf(l, t), fmaxf(rr, bt));
            float area = (bx.z - bx.x) * (bx.w - bx.y);
            bool ok = (mn > 0.0f) && (mx >= lo) && (mx <= hi);
            float m = ok ? area : INF_;
            if (m < best) { best = m; bi = g; }
        }

        const bool pos = best < INF_;
        float ctr = 0.0f, lbox = 0.0f, bce = 0.0f, posf = 0.0f, cls = 0.0f;
        if (pos) {
            posf = 1.0f;
            int lab = gt_labels[b * GNUM + bi] - 1;                 // 0..79
            float xx = pred_class[(size_t)k * 80 + lab];            // issue gather EARLY
            float4 bx = gb[bi];
            float wl = x - bx.x, wt = y - bx.y, wr = bx.z - x, wb = bx.w - y;

            float num = fminf(wl, wr) * fminf(wt, wb);
            float den = fmaxf(wl, wr) * fmaxf(wt, wb) + 1e-12f;
            ctr = __builtin_amdgcn_sqrtf(
                      fminf(fmaxf(num * __builtin_amdgcn_rcpf(den), 0.0f), 1.0f));

            float px1 = x - dpred.x, py1 = y - dpred.y, px2 = x + dpred.z, py2 = y + dpred.w;
            float tx1 = x - wl,  ty1 = y - wt,  tx2 = x + wr,  ty2 = y + wb;
            float ix1 = fmaxf(px1, tx1), iy1 = fmaxf(py1, ty1);
            float ix2 = fminf(px2, tx2), iy2 = fminf(py2, ty2);
            float inter = fmaxf(ix2 - ix1, 0.0f) * fmaxf(iy2 - iy1, 0.0f);
            float ap = fmaxf(px2 - px1, 0.0f) * fmaxf(py2 - py1, 0.0f);
            float at = fmaxf(tx2 - tx1, 0.0f) * fmaxf(ty2 - ty1, 0.0f);
            float iou = inter * __builtin_amdgcn_rcpf(ap + at - inter + 1e-7f);
            lbox = -__logf(fminf(fmaxf(iou, 1e-6f), 1.0f)) * ctr;

            float e  = __expf(-fabsf(pcv));
            float l1 = __logf(1.0f + e);
            float sp_p = fmaxf(pcv, 0.0f) + l1;
            float sp_n = fmaxf(-pcv, 0.0f) + l1;
            bce = ctr * sp_n + (1.0f - ctr) * sp_p;

            // focal correction for the target element:
            // streaming adds 0.75*nontarget for it; true value is 0.25*target.
            float s2c, aplc, bbc;
            sp_parts(xx, s2c, aplc, bbc);
            float nt = (xx >= 0.0f) ? aplc : bbc;
            float tg = (xx >= 0.0f) ? bbc : aplc;
            cls = s2c * fmaf(0.25f, tg, -0.75f * nt);
        }

        float v5[5] = {cls, lbox, bce, posf, ctr};
        #pragma unroll
        for (int off = 32; off >= 1; off >>= 1) {
            #pragma unroll
            for (int s2 = 0; s2 < 5; ++s2) v5[s2] += __shfl_down(v5[s2], off);
        }
        if (lane == 0) {
            #pragma unroll
            for (int s2 = 0; s2 < 5; ++s2) wpart[wid][s2] = v5[s2];
        }
        __syncthreads();
        if (tid == 0) {
            #pragma unroll
            for (int s2 = 0; s2 < 5; ++s2)
                partials[s2 * ABLK + a] =
                    (wpart[0][s2] + wpart[1][s2]) + (wpart[2][s2] + wpart[3][s2]);
        }
    }
}

__global__ __launch_bounds__(TPB_F) void fcos_final(
    const float* __restrict__ partials, float* __restrict__ out)
{
    const int tid = threadIdx.x;
    float acc[5] = {0, 0, 0, 0, 0};
    float accs = 0.0f;
    for (int i = tid; i < ABLK; i += TPB_F) {
        #pragma unroll
        for (int s2 = 0; s2 < 5; ++s2) acc[s2] += partials[s2 * ABLK + i];
    }
    for (int i = tid; i < SBLK * 4; i += TPB_F) accs += partials[5 * ABLK + i];
    #pragma unroll
    for (int off = 32; off >= 1; off >>= 1) {
        #pragma unroll
        for (int s2 = 0; s2 < 5; ++s2) acc[s2] += __shfl_down(acc[s2], off);
        accs += __shfl_down(accs, off);
    }
    __shared__ float wp[16][6];
    const int lane = tid & 63, wid = tid >> 6;
    if (lane == 0) {
        #pragma unroll
        for (int s2 = 0; s2 < 5; ++s2) wp[wid][s2] = acc[s2];
        wp[wid][5] = accs;
    }
    __syncthreads();
    if (tid == 0) {
        float S[6];
        #pragma unroll
        for (int s2 = 0; s2 < 6; ++s2) {
            float s = 0.0f;
            #pragma unroll
            for (int w = 0; w < 16; ++w) s += wp[w][s2];
            S[s2] = s;
        }
        float pos_num = fmaxf(S[3], 1.0f);
        float denorm  = fmaxf(S[4], 1e-6f);
        out[0] = fmaf(C_STREAM, S[5], S[0]) / pos_num;  // loss_cls
        out[1] = S[1] / denorm;                         // loss_box
        out[2] = S[2] / pos_num;                        // loss_ctr
    }
}

extern "C" void kernel_launch(void* const* d_in, const int* in_sizes, int n_in,
                              void* d_out, int out_size, void* d_ws, size_t ws_size,
                              hipStream_t stream) {
    const float*  pred_class = (const float*)d_in[0];
    const float4* pred_bbox  = (const float4*)d_in[1];
    const float*  pred_ctr   = (const float*)d_in[2];
    const float4* gt_boxes   = (const float4*)d_in[3];
    const int*    gt_labels  = (const int*)d_in[4];
    float* partials = (float*)d_ws;          // (5*ABLK + 4*SBLK) floats, fully rewritten
    float* out = (float*)d_out;

    fcos_fat<<<GRID, TPB, 0, stream>>>(pred_class, pred_bbox, pred_ctr,
                                       gt_boxes, gt_labels, partials);
    fcos_final<<<1, TPB_F, 0, stream>>>(partials, out);
}